// Round 2
// baseline (1561.949 us; speedup 1.0000x reference)
//
#include <hip/hip_runtime.h>
#include <cstdint>
#include <cstddef>

// ---------------------------------------------------------------------------
// SpikingCoreFlow: bit-exact replication of the JAX reference on MI355X.
//
// Dims (fixed by setup_inputs): B=128, D_in=1024, n_cores=64, N=256, A=256,
// n_out=10, cycles=32, pool_width = 1024 + 64*256 + 2 = 17410.
//
// Pool region "Pb" (bytes, one byte per 0/1 value, rows of 128 = B):
//   rows [0, 32768)        : spikes, row = t*1024 + d
//   rows [32768, 49152)    : buffer ping (A), row = 32768 + c*256 + n
//   rows [49152, 65536)    : buffer pong (B)
//   row 65536               : zeros column
//   row 65537               : ones column
// Cycle t reads parity A if t even, writes the other.
//
// Exactness assumptions (journal):
//  - threefry2x32 per jax._src.prng (20 rounds, rot {13,15,26,6},{17,29,16,24})
//  - RNG semantics: jax_threefry_partitionable=True (JAX >= 0.5 default):
//      split:  keys[t] = (w0, w1) of cipher(key, (0, t))
//      bits32: bits[f]  = w0 ^ w1 of cipher(key_t, (0, f)), f = flat index
//    (R1 used legacy semantics -> total divergence, absmax 28. If this round
//     still diverges: try bits = w1 only, then legacy again.)
//  - einsum 'cna,bca->cbn' on XLA-CPU accumulates a=0..255 ascending with a
//    single fused-FMA chain starting at 0; memb += E is a separate rounded add.
//    Since inp ∈ {0,1}, fmaf(w,m,acc) is bit-identical to that chain.
// ---------------------------------------------------------------------------

#define N_CORES   64
#define NN        256
#define AA        256
#define BB        128
#define DIN       1024
#define NOUT      10
#define CYCLES    32
#define ROW_SPK   0u
#define ROW_A     32768u
#define ROW_B     49152u
#define ROW_ZERO  65536u
#define ROW_ONE   65537u

__device__ __forceinline__ void tf_round(uint32_t& x0, uint32_t& x1, int r) {
    x0 += x1;
    x1 = (x1 << r) | (x1 >> (32 - r));
    x1 ^= x0;
}

__device__ __forceinline__ void threefry2x32(uint32_t k0, uint32_t k1,
                                             uint32_t c0, uint32_t c1,
                                             uint32_t& o0, uint32_t& o1) {
    uint32_t ks2 = k0 ^ k1 ^ 0x1BD11BDAu;
    uint32_t x0 = c0 + k0, x1 = c1 + k1;
    tf_round(x0,x1,13); tf_round(x0,x1,15); tf_round(x0,x1,26); tf_round(x0,x1,6);
    x0 += k1; x1 += ks2 + 1u;
    tf_round(x0,x1,17); tf_round(x0,x1,29); tf_round(x0,x1,16); tf_round(x0,x1,24);
    x0 += ks2; x1 += k0 + 2u;
    tf_round(x0,x1,13); tf_round(x0,x1,15); tf_round(x0,x1,26); tf_round(x0,x1,6);
    x0 += k0; x1 += k1 + 3u;
    tf_round(x0,x1,17); tf_round(x0,x1,29); tf_round(x0,x1,16); tf_round(x0,x1,24);
    x0 += k1; x1 += ks2 + 4u;
    tf_round(x0,x1,13); tf_round(x0,x1,15); tf_round(x0,x1,26); tf_round(x0,x1,6);
    x0 += ks2; x1 += k0 + 5u;
    o0 = x0; o1 = x1;
}

// spikes[t][b][d] = (uniform(keys[t])[b,d] < x[b,d]) -> byte, stored b-contig:
// Pb[(t*1024 + d)*128 + b].
// Partitionable semantics: key_t = cipher((0,42),(0,t)) [both words];
// bits for flat f = b*1024+d is w0^w1 of cipher(key_t, (0, f)).
__global__ void spikes_kernel(const float* __restrict__ x,
                              unsigned char* __restrict__ Pb) {
    __shared__ unsigned char S[32 * 132];   // [dl][b], padded row 132B
    int bx  = blockIdx.x;        // 1024 = 32 t * 32 dblk
    int t   = bx >> 5;
    int d0  = (bx & 31) * 32;
    int tid = threadIdx.x;

    uint32_t k0, k1;
    threefry2x32(0u, 42u, 0u, (uint32_t)t, k0, k1);   // keys[t] = (w0, w1)

    #pragma unroll
    for (int k = 0; k < 16; ++k) {
        int e  = tid + k * 256;      // 0..4095 = 128 bb * 32 dl
        int bb = e >> 5;
        int dl = e & 31;
        int d  = d0 + dl;
        uint32_t f = (uint32_t)(bb * 1024 + d);
        uint32_t y0, y1;
        threefry2x32(k0, k1, 0u, f, y0, y1);
        uint32_t bits = y0 ^ y1;                      // xor-fold (32-bit path)
        float u = __uint_as_float((bits >> 9) | 0x3f800000u) - 1.0f;
        S[dl * 132 + bb] = (u < x[bb * 1024 + d]) ? 1 : 0;
    }
    __syncthreads();

    int dl = tid >> 3;           // 0..31
    int bg = tid & 7;            // byte group *16
    const uint32_t* Srow = (const uint32_t*)(S + dl * 132);
    uint4 v;
    v.x = Srow[bg * 4 + 0]; v.y = Srow[bg * 4 + 1];
    v.z = Srow[bg * 4 + 2]; v.w = Srow[bg * 4 + 3];
    size_t row = (size_t)t * 1024 + d0 + dl;
    *(uint4*)(Pb + row * 128 + bg * 16) = v;
}

// WT[c][a][n] = W[c][n][a]  (so per-a weights are contiguous for s_load)
__global__ void wt_kernel(const float* __restrict__ W, float* __restrict__ WT) {
    __shared__ float T[32][33];
    int bx = blockIdx.x;            // 4096 = 64 c * 8 tn * 8 ta
    int c  = bx >> 6;
    int tn = (bx >> 3) & 7;
    int ta = bx & 7;
    int tid = threadIdx.x;
    int r  = tid >> 3;              // 0..31
    int q4 = (tid & 7) * 4;         // 0..28

    const float* src = W + (size_t)c * 65536 + (size_t)(tn * 32 + r) * 256 + ta * 32 + q4;
    float4 v = *(const float4*)src;
    T[r][q4 + 0] = v.x; T[r][q4 + 1] = v.y; T[r][q4 + 2] = v.z; T[r][q4 + 3] = v.w;
    __syncthreads();

    float4 o;
    o.x = T[q4 + 0][r]; o.y = T[q4 + 1][r]; o.z = T[q4 + 2][r]; o.w = T[q4 + 3][r];
    float* dst = WT + (size_t)c * 65536 + (size_t)(ta * 32 + r) * 256 + tn * 32 + q4;
    *(float4*)dst = o;
}

// off_tab[t][c][a] = byte offset of pool row for axon j at cycle t (READ parity)
// out_off[t][o]    = byte offset of pool2 row for out_src j (WRITE parity of t)
__global__ void offtab_kernel(const int* __restrict__ axon,
                              const int* __restrict__ outsrc,
                              uint32_t* __restrict__ off_tab,
                              uint32_t* __restrict__ out_off) {
    int bx = blockIdx.x;
    int tid = threadIdx.x;
    if (bx < 2048) {
        int idx = bx * 256 + tid;          // [t][c*256+a]
        int t   = idx >> 14;
        int ca  = idx & 16383;
        int j   = axon[ca];
        uint32_t row;
        if (j < 1024)        row = (uint32_t)(t * 1024 + j);
        else if (j < 17408)  row = (((t & 1) == 0) ? ROW_A : ROW_B) + (uint32_t)(j - 1024);
        else                 row = (j == 17408) ? ROW_ZERO : ROW_ONE;
        off_tab[idx] = row * 128u;
    } else {
        for (int idx = tid; idx < CYCLES * NOUT; idx += 256) {
            int t = idx / NOUT, o = idx % NOUT;
            int j = outsrc[o];
            uint32_t row;
            if (j < 1024)        row = (uint32_t)(t * 1024 + j);
            else if (j < 17408)  row = (((t & 1) == 0) ? ROW_B : ROW_A) + (uint32_t)(j - 1024);
            else                 row = (j == 17408) ? ROW_ZERO : ROW_ONE;
            out_off[idx] = row * 128u;
        }
    }
}

// One cycle. Block = (c, b-half, n-quarter): 64*2*4 = 512 blocks, 256 thr.
// Wave handles 16 consecutive n for 64 consecutive b (lane = b).
// Hot loop per a: uniform s_load of 16 weights + 1 coalesced byte mask load
// + 16 fmaf. Accumulation: a ascending, single chain from 0 (exactness!).
__global__ __launch_bounds__(256, 2) void core_kernel(
    const unsigned char* __restrict__ Pb,
    unsigned char* __restrict__ Pw,
    const float* __restrict__ WT,
    const uint32_t* __restrict__ off_t,
    float* __restrict__ memb,
    const float* __restrict__ thresholds,
    uint32_t wbyte_base,
    const uint32_t* __restrict__ out_off_prev,
    float* __restrict__ d_out,
    int do_out)
{
    int tid = threadIdx.x;
    int bx  = blockIdx.x;

    // fused out-update for the PREVIOUS cycle (reads buf written last kernel)
    if (do_out && bx == 511 && tid < BB) {
        #pragma unroll
        for (int o = 0; o < NOUT; ++o) {
            uint32_t off = out_off_prev[o];
            d_out[tid * NOUT + o] += (float)Pb[off + (uint32_t)tid];
        }
    }

    int c    = bx >> 3;
    int bh   = (bx >> 2) & 1;
    int nq   = bx & 3;
    int lane = tid & 63;
    int wid  = __builtin_amdgcn_readfirstlane(tid >> 6);
    int b    = bh * 64 + lane;
    int n0   = nq * 64 + wid * 16;

    float acc[16];
    #pragma unroll
    for (int k = 0; k < 16; ++k) acc[k] = 0.0f;

    const float*    wt   = WT + (size_t)c * 65536 + n0;
    const uint32_t* offs = off_t + c * 256;

    for (int a = 0; a < 256; ++a) {
        uint32_t off = offs[a];
        float m = (float)Pb[off + (uint32_t)b];
        const float* wp = wt + a * 256;
        #pragma unroll
        for (int k = 0; k < 16; ++k)
            acc[k] = fmaf(wp[k], m, acc[k]);
    }

    float thr = thresholds[c];
    int rowbase = c * 256 + n0;
    #pragma unroll
    for (int k = 0; k < 16; ++k) {
        size_t idx = (size_t)(rowbase + k) * 128 + b;
        float v = memb[idx] + acc[k];           // single rounded add (matches ref)
        bool fired = v > thr;
        memb[idx] = fired ? 0.0f : v;
        Pw[wbyte_base + idx] = fired ? (unsigned char)1 : (unsigned char)0;
    }
}

__global__ void tail_kernel(const unsigned char* __restrict__ Pb,
                            const uint32_t* __restrict__ out_off31,
                            float* __restrict__ d_out) {
    int tid = threadIdx.x;
    if (tid < BB) {
        #pragma unroll
        for (int o = 0; o < NOUT; ++o) {
            uint32_t off = out_off31[o];
            d_out[tid * NOUT + o] += (float)Pb[off + (uint32_t)tid];
        }
    }
}

extern "C" void kernel_launch(void* const* d_in, const int* in_sizes, int n_in,
                              void* d_out_, int out_size, void* d_ws, size_t ws_size,
                              hipStream_t stream) {
    const float* x          = (const float*)d_in[0];
    const float* W          = (const float*)d_in[1];
    const float* thresholds = (const float*)d_in[2];
    const int*   axon       = (const int*)d_in[3];
    const int*   outsrc     = (const int*)d_in[4];
    // d_in[5] = cycles (device scalar); fixed instance -> hardcoded 32.

    if (ws_size < (size_t)45 * 1024 * 1024) return;   // need ~44 MiB scratch

    unsigned char* ws      = (unsigned char*)d_ws;
    unsigned char* Pb      = ws;                                   // 8,388,864 B
    float*         WT      = (float*)(ws + (size_t)(16u << 20));   // 16 MiB
    uint32_t*      off_tab = (uint32_t*)(ws + (size_t)(32u << 20)); // 2 MiB
    uint32_t*      out_off = (uint32_t*)(ws + (size_t)(32u << 20) + 2u * 1024u * 1024u);
    float*         memb    = (float*)(ws + (size_t)(36u << 20));   // 8 MiB
    float*         out     = (float*)d_out_;

    // init (every launch: ws/out are poisoned once, never restored)
    hipMemsetAsync(memb, 0, (size_t)N_CORES * NN * BB * sizeof(float), stream);
    hipMemsetAsync(Pb + (size_t)ROW_A * 128, 0, (size_t)16384 * 128, stream);   // buf ping = 0
    hipMemsetAsync(Pb + (size_t)ROW_ZERO * 128, 0, 128, stream);                // zeros col
    hipMemsetAsync(Pb + (size_t)ROW_ONE * 128, 1, 128, stream);                 // ones col
    hipMemsetAsync(out, 0, (size_t)BB * NOUT * sizeof(float), stream);

    spikes_kernel<<<1024, 256, 0, stream>>>(x, Pb);
    wt_kernel<<<4096, 256, 0, stream>>>(W, WT);
    offtab_kernel<<<2049, 256, 0, stream>>>(axon, outsrc, off_tab, out_off);

    for (int t = 0; t < CYCLES; ++t) {
        uint32_t wrow = ((t & 1) == 0) ? ROW_B : ROW_A;   // write parity
        const uint32_t* oprev = out_off + (t > 0 ? (t - 1) * NOUT : 0);
        core_kernel<<<512, 256, 0, stream>>>(
            Pb, Pb, WT, off_tab + (size_t)t * 16384, memb, thresholds,
            wrow * 128u, oprev, out, t > 0 ? 1 : 0);
    }
    tail_kernel<<<1, 128, 0, stream>>>(Pb, out_off + 31 * NOUT, out);
}

// Round 3
// 669.753 us; speedup vs baseline: 2.3321x; 2.3321x over previous
//
#include <hip/hip_runtime.h>
#include <cstdint>
#include <cstddef>

// ---------------------------------------------------------------------------
// SpikingCoreFlow: bit-exact replication of the JAX reference on MI355X.
//
// Dims: B=128, D_in=1024, n_cores=64, N=256, A=256, n_out=10, cycles=32,
// pool_width = 17410.
//
// Pool "Pb" (bytes, rows of 128 = B):
//   rows [0, 32768)        : spikes, row = t*1024 + d
//   rows [32768, 49152)    : buffer ping (A), row = 32768 + c*256 + n
//   rows [49152, 65536)    : buffer pong (B)
//   row 65536 / 65537      : zeros / ones columns
// Cycle t reads parity A if t even, writes the other.
//
// Exactness (verified R2, absmax == 0.0):
//  - threefry2x32 with jax_threefry_partitionable=True semantics:
//      split:  keys[t] = (w0, w1) of cipher(key, (0, t))
//      bits32: bits[f] = w0 ^ w1 of cipher(key_t, (0, f))
//  - einsum 'cna,bca->cbn' = single ascending-a fused-FMA chain from 0;
//    memb += E is one more rounded add. DO NOT split the a-chain.
//
// R3 perf change: core_kernel was latency-bound (VALUBusy 16%, 470 cy/iter:
// dependent offs->mask VMEM chain). Masks are now pre-gathered per block into
// LDS as floats (padded stride 65 dwords, conflict-free ds_read_b32), inner
// loop = 1 ds_read + 16 scalar-fed FMA, unroll 4. XCD swizzle groups 8 c's
// per XCD so each XCD's WT working set (2 MB) is L2-resident.
// ---------------------------------------------------------------------------

#define N_CORES   64
#define NN        256
#define AA        256
#define BB        128
#define DIN       1024
#define NOUT      10
#define CYCLES    32
#define ROW_SPK   0u
#define ROW_A     32768u
#define ROW_B     49152u
#define ROW_ZERO  65536u
#define ROW_ONE   65537u

__device__ __forceinline__ void tf_round(uint32_t& x0, uint32_t& x1, int r) {
    x0 += x1;
    x1 = (x1 << r) | (x1 >> (32 - r));
    x1 ^= x0;
}

__device__ __forceinline__ void threefry2x32(uint32_t k0, uint32_t k1,
                                             uint32_t c0, uint32_t c1,
                                             uint32_t& o0, uint32_t& o1) {
    uint32_t ks2 = k0 ^ k1 ^ 0x1BD11BDAu;
    uint32_t x0 = c0 + k0, x1 = c1 + k1;
    tf_round(x0,x1,13); tf_round(x0,x1,15); tf_round(x0,x1,26); tf_round(x0,x1,6);
    x0 += k1; x1 += ks2 + 1u;
    tf_round(x0,x1,17); tf_round(x0,x1,29); tf_round(x0,x1,16); tf_round(x0,x1,24);
    x0 += ks2; x1 += k0 + 2u;
    tf_round(x0,x1,13); tf_round(x0,x1,15); tf_round(x0,x1,26); tf_round(x0,x1,6);
    x0 += k0; x1 += k1 + 3u;
    tf_round(x0,x1,17); tf_round(x0,x1,29); tf_round(x0,x1,16); tf_round(x0,x1,24);
    x0 += k1; x1 += ks2 + 4u;
    tf_round(x0,x1,13); tf_round(x0,x1,15); tf_round(x0,x1,26); tf_round(x0,x1,6);
    x0 += ks2; x1 += k0 + 5u;
    o0 = x0; o1 = x1;
}

__global__ void spikes_kernel(const float* __restrict__ x,
                              unsigned char* __restrict__ Pb) {
    __shared__ unsigned char S[32 * 132];
    int bx  = blockIdx.x;        // 1024 = 32 t * 32 dblk
    int t   = bx >> 5;
    int d0  = (bx & 31) * 32;
    int tid = threadIdx.x;

    uint32_t k0, k1;
    threefry2x32(0u, 42u, 0u, (uint32_t)t, k0, k1);   // keys[t] = (w0, w1)

    #pragma unroll
    for (int k = 0; k < 16; ++k) {
        int e  = tid + k * 256;      // 0..4095 = 128 bb * 32 dl
        int bb = e >> 5;
        int dl = e & 31;
        int d  = d0 + dl;
        uint32_t f = (uint32_t)(bb * 1024 + d);
        uint32_t y0, y1;
        threefry2x32(k0, k1, 0u, f, y0, y1);
        uint32_t bits = y0 ^ y1;                      // xor-fold
        float u = __uint_as_float((bits >> 9) | 0x3f800000u) - 1.0f;
        S[dl * 132 + bb] = (u < x[bb * 1024 + d]) ? 1 : 0;
    }
    __syncthreads();

    int dl = tid >> 3;
    int bg = tid & 7;
    const uint32_t* Srow = (const uint32_t*)(S + dl * 132);
    uint4 v;
    v.x = Srow[bg * 4 + 0]; v.y = Srow[bg * 4 + 1];
    v.z = Srow[bg * 4 + 2]; v.w = Srow[bg * 4 + 3];
    size_t row = (size_t)t * 1024 + d0 + dl;
    *(uint4*)(Pb + row * 128 + bg * 16) = v;
}

// WT[c][a][n] = W[c][n][a]
__global__ void wt_kernel(const float* __restrict__ W, float* __restrict__ WT) {
    __shared__ float T[32][33];
    int bx = blockIdx.x;            // 4096 = 64 c * 8 tn * 8 ta
    int c  = bx >> 6;
    int tn = (bx >> 3) & 7;
    int ta = bx & 7;
    int tid = threadIdx.x;
    int r  = tid >> 3;
    int q4 = (tid & 7) * 4;

    const float* src = W + (size_t)c * 65536 + (size_t)(tn * 32 + r) * 256 + ta * 32 + q4;
    float4 v = *(const float4*)src;
    T[r][q4 + 0] = v.x; T[r][q4 + 1] = v.y; T[r][q4 + 2] = v.z; T[r][q4 + 3] = v.w;
    __syncthreads();

    float4 o;
    o.x = T[q4 + 0][r]; o.y = T[q4 + 1][r]; o.z = T[q4 + 2][r]; o.w = T[q4 + 3][r];
    float* dst = WT + (size_t)c * 65536 + (size_t)(ta * 32 + r) * 256 + tn * 32 + q4;
    *(float4*)dst = o;
}

__global__ void offtab_kernel(const int* __restrict__ axon,
                              const int* __restrict__ outsrc,
                              uint32_t* __restrict__ off_tab,
                              uint32_t* __restrict__ out_off) {
    int bx = blockIdx.x;
    int tid = threadIdx.x;
    if (bx < 2048) {
        int idx = bx * 256 + tid;          // [t][c*256+a]
        int t   = idx >> 14;
        int ca  = idx & 16383;
        int j   = axon[ca];
        uint32_t row;
        if (j < 1024)        row = (uint32_t)(t * 1024 + j);
        else if (j < 17408)  row = (((t & 1) == 0) ? ROW_A : ROW_B) + (uint32_t)(j - 1024);
        else                 row = (j == 17408) ? ROW_ZERO : ROW_ONE;
        off_tab[idx] = row * 128u;
    } else {
        for (int idx = tid; idx < CYCLES * NOUT; idx += 256) {
            int t = idx / NOUT, o = idx % NOUT;
            int j = outsrc[o];
            uint32_t row;
            if (j < 1024)        row = (uint32_t)(t * 1024 + j);
            else if (j < 17408)  row = (((t & 1) == 0) ? ROW_B : ROW_A) + (uint32_t)(j - 1024);
            else                 row = (j == 17408) ? ROW_ZERO : ROW_ONE;
            out_off[idx] = row * 128u;
        }
    }
}

// One cycle. 512 blocks x 256 thr. Block = (c, bh, nq) via XCD-grouping
// swizzle (XCD = bx&7 gets c in [8*xcd, 8*xcd+8) -> 2 MB WT slice, L2-fit).
// Phase 1: gather 256 mask bytes for (c,bh) -> LDS floats (stride 65 dwords).
// Phase 2: per wave 16 n, a-loop = ds_read_b32 + 16 fmaf (ascending chain).
__global__ __launch_bounds__(256, 2) void core_kernel(
    const unsigned char* __restrict__ Pb,
    unsigned char* __restrict__ Pw,
    const float* __restrict__ WT,
    const uint32_t* __restrict__ off_t,
    float* __restrict__ memb,
    const float* __restrict__ thresholds,
    uint32_t wbyte_base,
    const uint32_t* __restrict__ out_off_prev,
    float* __restrict__ d_out,
    int do_out)
{
    __shared__ float Mf[256 * 65];     // [a][lane], row stride 65 dwords (65 KB)

    int tid = threadIdx.x;
    int bx  = blockIdx.x;

    // fused out-update for the PREVIOUS cycle (reads buf written last kernel)
    if (do_out && bx == 511 && tid < BB) {
        #pragma unroll
        for (int o = 0; o < NOUT; ++o) {
            uint32_t off = out_off_prev[o];
            d_out[tid * NOUT + o] += (float)Pb[off + (uint32_t)tid];
        }
    }

    // XCD-grouping decode (bijective on [0,512))
    int xcd  = bx & 7;
    int rest = bx >> 3;            // 0..63
    int c    = xcd * 8 + (rest & 7);
    int bhnq = rest >> 3;          // 0..7
    int bh   = bhnq >> 2;
    int nq   = bhnq & 3;

    // ---- Phase 1: mask gather -> LDS floats ----
    {
        uint32_t off = off_t[c * 256 + tid];            // coalesced
        const unsigned char* src = Pb + off + bh * 64;
        float* dst = Mf + tid * 65;
        #pragma unroll
        for (int j = 0; j < 4; ++j) {
            uint4 v = *(const uint4*)(src + j * 16);
            const unsigned char* pb = (const unsigned char*)&v;
            #pragma unroll
            for (int q = 0; q < 16; ++q)
                dst[j * 16 + q] = (float)pb[q];
        }
    }
    __syncthreads();

    int lane = tid & 63;
    int wid  = __builtin_amdgcn_readfirstlane(tid >> 6);
    int b    = bh * 64 + lane;
    int n0   = nq * 64 + wid * 16;

    float acc[16];
    #pragma unroll
    for (int k = 0; k < 16; ++k) acc[k] = 0.0f;

    const float* wt = WT + (size_t)c * 65536 + n0;

    // ---- Phase 2: the exact ascending-a FMA chain ----
    #pragma unroll 4
    for (int a = 0; a < 256; ++a) {
        float m = Mf[a * 65 + lane];                    // conflict-free
        const float* wp = wt + (size_t)a * 256;         // wave-uniform -> s_load
        #pragma unroll
        for (int k = 0; k < 16; ++k)
            acc[k] = fmaf(wp[k], m, acc[k]);
    }

    float thr = thresholds[c];
    int rowbase = c * 256 + n0;
    #pragma unroll
    for (int k = 0; k < 16; ++k) {
        size_t idx = (size_t)(rowbase + k) * 128 + b;
        float v = memb[idx] + acc[k];                   // single rounded add
        bool fired = v > thr;
        memb[idx] = fired ? 0.0f : v;
        Pw[wbyte_base + idx] = fired ? (unsigned char)1 : (unsigned char)0;
    }
}

__global__ void tail_kernel(const unsigned char* __restrict__ Pb,
                            const uint32_t* __restrict__ out_off31,
                            float* __restrict__ d_out) {
    int tid = threadIdx.x;
    if (tid < BB) {
        #pragma unroll
        for (int o = 0; o < NOUT; ++o) {
            uint32_t off = out_off31[o];
            d_out[tid * NOUT + o] += (float)Pb[off + (uint32_t)tid];
        }
    }
}

extern "C" void kernel_launch(void* const* d_in, const int* in_sizes, int n_in,
                              void* d_out_, int out_size, void* d_ws, size_t ws_size,
                              hipStream_t stream) {
    const float* x          = (const float*)d_in[0];
    const float* W          = (const float*)d_in[1];
    const float* thresholds = (const float*)d_in[2];
    const int*   axon       = (const int*)d_in[3];
    const int*   outsrc     = (const int*)d_in[4];
    // d_in[5] = cycles; fixed instance -> 32.

    if (ws_size < (size_t)45 * 1024 * 1024) return;

    unsigned char* ws      = (unsigned char*)d_ws;
    unsigned char* Pb      = ws;                                    // 8.4 MB
    float*         WT      = (float*)(ws + (size_t)(16u << 20));    // 16 MiB
    uint32_t*      off_tab = (uint32_t*)(ws + (size_t)(32u << 20)); // 2 MiB
    uint32_t*      out_off = (uint32_t*)(ws + (size_t)(32u << 20) + 2u * 1024u * 1024u);
    float*         memb    = (float*)(ws + (size_t)(36u << 20));    // 8 MiB
    float*         out     = (float*)d_out_;

    hipMemsetAsync(memb, 0, (size_t)N_CORES * NN * BB * sizeof(float), stream);
    hipMemsetAsync(Pb + (size_t)ROW_A * 128, 0, (size_t)16384 * 128, stream);
    hipMemsetAsync(Pb + (size_t)ROW_ZERO * 128, 0, 128, stream);
    hipMemsetAsync(Pb + (size_t)ROW_ONE * 128, 1, 128, stream);
    hipMemsetAsync(out, 0, (size_t)BB * NOUT * sizeof(float), stream);

    spikes_kernel<<<1024, 256, 0, stream>>>(x, Pb);
    wt_kernel<<<4096, 256, 0, stream>>>(W, WT);
    offtab_kernel<<<2049, 256, 0, stream>>>(axon, outsrc, off_tab, out_off);

    for (int t = 0; t < CYCLES; ++t) {
        uint32_t wrow = ((t & 1) == 0) ? ROW_B : ROW_A;   // write parity
        const uint32_t* oprev = out_off + (t > 0 ? (t - 1) * NOUT : 0);
        core_kernel<<<512, 256, 0, stream>>>(
            Pb, Pb, WT, off_tab + (size_t)t * 16384, memb, thresholds,
            wrow * 128u, oprev, out, t > 0 ? 1 : 0);
    }
    tail_kernel<<<1, 128, 0, stream>>>(Pb, out_off + 31 * NOUT, out);
}

// Round 4
// 648.113 us; speedup vs baseline: 2.4100x; 1.0334x over previous
//
#include <hip/hip_runtime.h>
#include <cstdint>
#include <cstddef>

// ---------------------------------------------------------------------------
// SpikingCoreFlow: bit-exact replication of the JAX reference on MI355X.
//
// Dims: B=128, D_in=1024, n_cores=64, N=256, A=256, n_out=10, cycles=32,
// pool_width = 17410.
//
// Pool "Pb" (bytes, rows of 128 = B):
//   rows [0, 32768)        : spikes, row = t*1024 + d
//   rows [32768, 49152)    : buffer ping (A), row = 32768 + c*256 + n
//   rows [49152, 65536)    : buffer pong (B)
//   row 65536 / 65537      : zeros / ones columns
// Cycle t reads parity A if t even, writes the other.
//
// Exactness (verified R2/R3, absmax == 0.0):
//  - threefry2x32 with jax_threefry_partitionable=True semantics:
//      split:  keys[t] = (w0, w1) of cipher(key, (0, t))
//      bits32: bits[f] = w0 ^ w1 of cipher(key_t, (0, f))
//  - einsum 'cna,bca->cbn' = single ascending-a fused-FMA chain from 0;
//    memb += E is one more rounded add. v_pk_fma_f32 = 2 independent IEEE
//    FMAs -> per-n chain unchanged -> still bit-exact.
//
// R4 perf change: R3's core (~20us) was serialized on s_load_dwordx16 latency
// (~200cy/iter, K$ misses every iter; post-mortem matched exactly). Weights
// now come via wave-uniform global_load_dwordx4 (VMEM -> VGPRs, HW broadcast,
// compiler pipelines vmcnt-counted prefetch deeply), and the 16 FMAs/iter are
// packed as 8 v_pk_fma_f32 via float2 __builtin_elementwise_fma.
// ---------------------------------------------------------------------------

#define N_CORES   64
#define NN        256
#define AA        256
#define BB        128
#define DIN       1024
#define NOUT      10
#define CYCLES    32
#define ROW_SPK   0u
#define ROW_A     32768u
#define ROW_B     49152u
#define ROW_ZERO  65536u
#define ROW_ONE   65537u

typedef float v2f __attribute__((ext_vector_type(2)));

__device__ __forceinline__ void tf_round(uint32_t& x0, uint32_t& x1, int r) {
    x0 += x1;
    x1 = (x1 << r) | (x1 >> (32 - r));
    x1 ^= x0;
}

__device__ __forceinline__ void threefry2x32(uint32_t k0, uint32_t k1,
                                             uint32_t c0, uint32_t c1,
                                             uint32_t& o0, uint32_t& o1) {
    uint32_t ks2 = k0 ^ k1 ^ 0x1BD11BDAu;
    uint32_t x0 = c0 + k0, x1 = c1 + k1;
    tf_round(x0,x1,13); tf_round(x0,x1,15); tf_round(x0,x1,26); tf_round(x0,x1,6);
    x0 += k1; x1 += ks2 + 1u;
    tf_round(x0,x1,17); tf_round(x0,x1,29); tf_round(x0,x1,16); tf_round(x0,x1,24);
    x0 += ks2; x1 += k0 + 2u;
    tf_round(x0,x1,13); tf_round(x0,x1,15); tf_round(x0,x1,26); tf_round(x0,x1,6);
    x0 += k0; x1 += k1 + 3u;
    tf_round(x0,x1,17); tf_round(x0,x1,29); tf_round(x0,x1,16); tf_round(x0,x1,24);
    x0 += k1; x1 += ks2 + 4u;
    tf_round(x0,x1,13); tf_round(x0,x1,15); tf_round(x0,x1,26); tf_round(x0,x1,6);
    x0 += ks2; x1 += k0 + 5u;
    o0 = x0; o1 = x1;
}

__global__ void spikes_kernel(const float* __restrict__ x,
                              unsigned char* __restrict__ Pb) {
    __shared__ unsigned char S[32 * 132];
    int bx  = blockIdx.x;        // 1024 = 32 t * 32 dblk
    int t   = bx >> 5;
    int d0  = (bx & 31) * 32;
    int tid = threadIdx.x;

    uint32_t k0, k1;
    threefry2x32(0u, 42u, 0u, (uint32_t)t, k0, k1);   // keys[t] = (w0, w1)

    #pragma unroll
    for (int k = 0; k < 16; ++k) {
        int e  = tid + k * 256;      // 0..4095 = 128 bb * 32 dl
        int bb = e >> 5;
        int dl = e & 31;
        int d  = d0 + dl;
        uint32_t f = (uint32_t)(bb * 1024 + d);
        uint32_t y0, y1;
        threefry2x32(k0, k1, 0u, f, y0, y1);
        uint32_t bits = y0 ^ y1;                      // xor-fold
        float u = __uint_as_float((bits >> 9) | 0x3f800000u) - 1.0f;
        S[dl * 132 + bb] = (u < x[bb * 1024 + d]) ? 1 : 0;
    }
    __syncthreads();

    int dl = tid >> 3;
    int bg = tid & 7;
    const uint32_t* Srow = (const uint32_t*)(S + dl * 132);
    uint4 v;
    v.x = Srow[bg * 4 + 0]; v.y = Srow[bg * 4 + 1];
    v.z = Srow[bg * 4 + 2]; v.w = Srow[bg * 4 + 3];
    size_t row = (size_t)t * 1024 + d0 + dl;
    *(uint4*)(Pb + row * 128 + bg * 16) = v;
}

// WT[c][a][n] = W[c][n][a]
__global__ void wt_kernel(const float* __restrict__ W, float* __restrict__ WT) {
    __shared__ float T[32][33];
    int bx = blockIdx.x;            // 4096 = 64 c * 8 tn * 8 ta
    int c  = bx >> 6;
    int tn = (bx >> 3) & 7;
    int ta = bx & 7;
    int tid = threadIdx.x;
    int r  = tid >> 3;
    int q4 = (tid & 7) * 4;

    const float* src = W + (size_t)c * 65536 + (size_t)(tn * 32 + r) * 256 + ta * 32 + q4;
    float4 v = *(const float4*)src;
    T[r][q4 + 0] = v.x; T[r][q4 + 1] = v.y; T[r][q4 + 2] = v.z; T[r][q4 + 3] = v.w;
    __syncthreads();

    float4 o;
    o.x = T[q4 + 0][r]; o.y = T[q4 + 1][r]; o.z = T[q4 + 2][r]; o.w = T[q4 + 3][r];
    float* dst = WT + (size_t)c * 65536 + (size_t)(ta * 32 + r) * 256 + tn * 32 + q4;
    *(float4*)dst = o;
}

__global__ void offtab_kernel(const int* __restrict__ axon,
                              const int* __restrict__ outsrc,
                              uint32_t* __restrict__ off_tab,
                              uint32_t* __restrict__ out_off) {
    int bx = blockIdx.x;
    int tid = threadIdx.x;
    if (bx < 2048) {
        int idx = bx * 256 + tid;          // [t][c*256+a]
        int t   = idx >> 14;
        int ca  = idx & 16383;
        int j   = axon[ca];
        uint32_t row;
        if (j < 1024)        row = (uint32_t)(t * 1024 + j);
        else if (j < 17408)  row = (((t & 1) == 0) ? ROW_A : ROW_B) + (uint32_t)(j - 1024);
        else                 row = (j == 17408) ? ROW_ZERO : ROW_ONE;
        off_tab[idx] = row * 128u;
    } else {
        for (int idx = tid; idx < CYCLES * NOUT; idx += 256) {
            int t = idx / NOUT, o = idx % NOUT;
            int j = outsrc[o];
            uint32_t row;
            if (j < 1024)        row = (uint32_t)(t * 1024 + j);
            else if (j < 17408)  row = (((t & 1) == 0) ? ROW_B : ROW_A) + (uint32_t)(j - 1024);
            else                 row = (j == 17408) ? ROW_ZERO : ROW_ONE;
            out_off[idx] = row * 128u;
        }
    }
}

// One cycle. 512 blocks x 256 thr. Block = (c, bh, nq) via XCD-grouping
// swizzle. Phase 1: gather 256 mask bytes for (c,bh) -> LDS floats (stride 65
// dwords, conflict-free). Phase 2: per wave 16 n; per a: 1 ds_read_b32 (mask)
// + 4 wave-uniform global_load_dwordx4 (weights, L2-broadcast, deep vmcnt
// pipeline) + 8 v_pk_fma_f32 (ascending-a chain per n, bit-exact).
__global__ __launch_bounds__(256, 2) void core_kernel(
    const unsigned char* __restrict__ Pb,
    unsigned char* __restrict__ Pw,
    const float* __restrict__ WT,
    const uint32_t* __restrict__ off_t,
    float* __restrict__ memb,
    const float* __restrict__ thresholds,
    uint32_t wbyte_base,
    const uint32_t* __restrict__ out_off_prev,
    float* __restrict__ d_out,
    int do_out)
{
    __shared__ float Mf[256 * 65];     // [a][lane], row stride 65 dwords

    int tid = threadIdx.x;
    int bx  = blockIdx.x;

    // fused out-update for the PREVIOUS cycle (reads buf written last kernel)
    if (do_out && bx == 511 && tid < BB) {
        #pragma unroll
        for (int o = 0; o < NOUT; ++o) {
            uint32_t off = out_off_prev[o];
            d_out[tid * NOUT + o] += (float)Pb[off + (uint32_t)tid];
        }
    }

    // XCD-grouping decode (bijective on [0,512))
    int xcd  = bx & 7;
    int rest = bx >> 3;            // 0..63
    int c    = xcd * 8 + (rest & 7);
    int bhnq = rest >> 3;          // 0..7
    int bh   = bhnq >> 2;
    int nq   = bhnq & 3;

    // ---- Phase 1: mask gather -> LDS floats (thread tid = axon a) ----
    {
        uint32_t off = off_t[c * 256 + tid];            // coalesced
        const unsigned char* src = Pb + off + bh * 64;
        float* dst = Mf + tid * 65;
        #pragma unroll
        for (int j = 0; j < 4; ++j) {
            uint4 v = *(const uint4*)(src + j * 16);
            const unsigned char* pb = (const unsigned char*)&v;
            #pragma unroll
            for (int q = 0; q < 16; ++q)
                dst[j * 16 + q] = (float)pb[q];
        }
    }
    __syncthreads();

    int lane = tid & 63;
    int wid  = __builtin_amdgcn_readfirstlane(tid >> 6);
    int b    = bh * 64 + lane;
    int n0   = nq * 64 + wid * 16;

    v2f acc2[8];
    #pragma unroll
    for (int j = 0; j < 8; ++j) acc2[j] = (v2f){0.0f, 0.0f};

    const float* wt = WT + (size_t)c * 65536 + n0;   // wave-uniform base

    // ---- Phase 2: exact ascending-a chain, pk-packed over n-pairs ----
    #pragma unroll 8
    for (int a = 0; a < 256; ++a) {
        float m = Mf[a * 65 + lane];                 // conflict-free ds_read
        v2f m2 = {m, m};
        const float4* wp4 = (const float4*)(wt + (size_t)a * 256);  // uniform
        float4 w0 = wp4[0];
        float4 w1 = wp4[1];
        float4 w2 = wp4[2];
        float4 w3 = wp4[3];
        acc2[0] = __builtin_elementwise_fma((v2f){w0.x, w0.y}, m2, acc2[0]);
        acc2[1] = __builtin_elementwise_fma((v2f){w0.z, w0.w}, m2, acc2[1]);
        acc2[2] = __builtin_elementwise_fma((v2f){w1.x, w1.y}, m2, acc2[2]);
        acc2[3] = __builtin_elementwise_fma((v2f){w1.z, w1.w}, m2, acc2[3]);
        acc2[4] = __builtin_elementwise_fma((v2f){w2.x, w2.y}, m2, acc2[4]);
        acc2[5] = __builtin_elementwise_fma((v2f){w2.z, w2.w}, m2, acc2[5]);
        acc2[6] = __builtin_elementwise_fma((v2f){w3.x, w3.y}, m2, acc2[6]);
        acc2[7] = __builtin_elementwise_fma((v2f){w3.z, w3.w}, m2, acc2[7]);
    }

    float thr = thresholds[c];
    int rowbase = c * 256 + n0;
    #pragma unroll
    for (int j = 0; j < 8; ++j) {
        #pragma unroll
        for (int h = 0; h < 2; ++h) {
            int k = 2 * j + h;
            float a = (h == 0) ? acc2[j].x : acc2[j].y;
            size_t idx = (size_t)(rowbase + k) * 128 + b;
            float v = memb[idx] + a;                // single rounded add
            bool fired = v > thr;
            memb[idx] = fired ? 0.0f : v;
            Pw[wbyte_base + idx] = fired ? (unsigned char)1 : (unsigned char)0;
        }
    }
}

__global__ void tail_kernel(const unsigned char* __restrict__ Pb,
                            const uint32_t* __restrict__ out_off31,
                            float* __restrict__ d_out) {
    int tid = threadIdx.x;
    if (tid < BB) {
        #pragma unroll
        for (int o = 0; o < NOUT; ++o) {
            uint32_t off = out_off31[o];
            d_out[tid * NOUT + o] += (float)Pb[off + (uint32_t)tid];
        }
    }
}

extern "C" void kernel_launch(void* const* d_in, const int* in_sizes, int n_in,
                              void* d_out_, int out_size, void* d_ws, size_t ws_size,
                              hipStream_t stream) {
    const float* x          = (const float*)d_in[0];
    const float* W          = (const float*)d_in[1];
    const float* thresholds = (const float*)d_in[2];
    const int*   axon       = (const int*)d_in[3];
    const int*   outsrc     = (const int*)d_in[4];
    // d_in[5] = cycles; fixed instance -> 32.

    if (ws_size < (size_t)45 * 1024 * 1024) return;

    unsigned char* ws      = (unsigned char*)d_ws;
    unsigned char* Pb      = ws;                                    // 8.4 MB
    float*         WT      = (float*)(ws + (size_t)(16u << 20));    // 16 MiB
    uint32_t*      off_tab = (uint32_t*)(ws + (size_t)(32u << 20)); // 2 MiB
    uint32_t*      out_off = (uint32_t*)(ws + (size_t)(32u << 20) + 2u * 1024u * 1024u);
    float*         memb    = (float*)(ws + (size_t)(36u << 20));    // 8 MiB
    float*         out     = (float*)d_out_;

    hipMemsetAsync(memb, 0, (size_t)N_CORES * NN * BB * sizeof(float), stream);
    hipMemsetAsync(Pb + (size_t)ROW_A * 128, 0, (size_t)16384 * 128, stream);
    hipMemsetAsync(Pb + (size_t)ROW_ZERO * 128, 0, 128, stream);
    hipMemsetAsync(Pb + (size_t)ROW_ONE * 128, 1, 128, stream);
    hipMemsetAsync(out, 0, (size_t)BB * NOUT * sizeof(float), stream);

    spikes_kernel<<<1024, 256, 0, stream>>>(x, Pb);
    wt_kernel<<<4096, 256, 0, stream>>>(W, WT);
    offtab_kernel<<<2049, 256, 0, stream>>>(axon, outsrc, off_tab, out_off);

    for (int t = 0; t < CYCLES; ++t) {
        uint32_t wrow = ((t & 1) == 0) ? ROW_B : ROW_A;   // write parity
        const uint32_t* oprev = out_off + (t > 0 ? (t - 1) * NOUT : 0);
        core_kernel<<<512, 256, 0, stream>>>(
            Pb, Pb, WT, off_tab + (size_t)t * 16384, memb, thresholds,
            wrow * 128u, oprev, out, t > 0 ? 1 : 0);
    }
    tail_kernel<<<1, 128, 0, stream>>>(Pb, out_off + 31 * NOUT, out);
}